// Round 6
// baseline (158.361 us; speedup 1.0000x reference)
//
#include <hip/hip_runtime.h>
#include <hip/hip_bf16.h>

// 3D bilateral filter, radius 2 (125 taps), input (2,1,128,128,128) f32.
// v6: v5's Schraudolph TAP (6 plain VALU, saturating cvt = OOB mask) with
// 8 voxels/thread (32x8x8 tile, 36x12x12 LDS), 16 accumulator chains,
// explicit next-row register prefetch (3x ds_read_b128 hidden under 40 taps),
// and __launch_bounds__(256,2) so the allocator isn't starved at 36 VGPRs.
// v5 evidence: VALU-busy ~206k cyc/SIMD vs 102k modeled -> scheduling/ILP
// starvation suspected; this round forces ILP. If it doesn't move, the
// per-inst cost model is wrong and round 7 goes packed-f16.

#define RADIUS 2
#define N 128
#define TX 32
#define TY 8
#define TZ 8
#define VPT 8                         // voxels per thread along x
#define PITCH (TX + 2 * RADIUS)       // 36 words; 144 B rows (16B-aligned)
#define LYD (TY + 2 * RADIUS)         // 12
#define LZD (TZ + 2 * RADIUS)         // 12
#define LDS_SIZE (PITCH * LYD * LZD)  // 5184 floats = 20.25 KB

#define LOG2E 1.4426950408889634f
#define BIG 1.0e18f
#define EXP2_SCALE 8388608.0f         // 2^23
#define EXP2_BIAS 1065353216.0f       // 127 * 2^23

__global__ __launch_bounds__(256, 2) void bilateral3d_kernel(
    const float* __restrict__ in, const float* __restrict__ p_sx,
    const float* __restrict__ p_sy, const float* __restrict__ p_sz,
    const float* __restrict__ p_cs, float* __restrict__ out) {
  __shared__ float s[LDS_SIZE];

  const int tid = threadIdx.x;
  const int x0 = blockIdx.x * TX;
  const int y0 = blockIdx.y * TY;
  const int zb = blockIdx.z;  // low 4 bits = z-tile, bit 4 = batch
  const int z0 = (zb & 15) * TZ;
  const int b = zb >> 4;

  const float* vol = in + (size_t)b * (N * N * N);

  // --- stage 36x12x12 halo tile (OOB -> sentinel) ---
  for (int i = tid; i < LDS_SIZE; i += 256) {
    int lx = i % PITCH;
    int t = i / PITCH;
    int ly = t % LYD;
    int lz = t / LYD;
    int gx = x0 + lx - RADIUS;
    int gy = y0 + ly - RADIUS;
    int gz = z0 + lz - RADIUS;
    float v = BIG;
    if ((unsigned)gx < N && (unsigned)gy < N && (unsigned)gz < N)
      v = vol[((size_t)gz * N + gy) * N + gx];
    s[i] = v;
  }
  __syncthreads();

  const int tx = tid & 3;         // x-group: voxels x0+8tx .. x0+8tx+7
  const int ty = (tid >> 2) & 7;
  const int tz = tid >> 5;

  // coefficients in exp2 units, pre-scaled by 2^23 for the bit-trick
  const float sxv = p_sx[0], syv = p_sy[0], szv = p_sz[0], csv = p_cs[0];
  const float AX2 = EXP2_SCALE * LOG2E / (2.0f * sxv * sxv);
  const float AY2 = EXP2_SCALE * LOG2E / (2.0f * syv * syv);
  const float AZ2 = EXP2_SCALE * LOG2E / (2.0f * szv * szv);
  const float NAC2 = -(EXP2_SCALE * LOG2E) / (2.0f * csv * csv);
  const float AX2_4 = 4.0f * AX2;

  const int xw = VPT * tx;  // word offset of this thread's 12-float tap window
  const int yb = ty + RADIUS;

  // center values: words [xw+2 .. xw+9] of the (dz=0,dy=0) row
  const int cbase = ((tz + RADIUS) * LYD + yb) * PITCH + xw;
  const float4 K0 = *(const float4*)&s[cbase];
  const float4 K1 = *(const float4*)&s[cbase + 4];
  const float4 K2 = *(const float4*)&s[cbase + 8];
  const float xc0 = K0.z, xc1 = K0.w, xc2 = K1.x, xc3 = K1.y;
  const float xc4 = K1.z, xc5 = K1.w, xc6 = K2.x, xc7 = K2.y;

  float n0 = 0, n1 = 0, n2 = 0, n3 = 0, n4 = 0, n5 = 0, n6 = 0, n7 = 0;
  float e0 = 0, e1 = 0, e2 = 0, e3 = 0, e4 = 0, e5 = 0, e6 = 0, e7 = 0;

#define TAP(XC, FV, CC, NN, DD)                          \
  {                                                      \
    float _d = (XC) - (FV);                              \
    float _f = fmaf(_d * _d, NAC2, (CC));                \
    unsigned _q;                                         \
    asm("v_cvt_u32_f32 %0, %1" : "=v"(_q) : "v"(_f));    \
    float _w = __uint_as_float(_q);                      \
    DD += _w;                                            \
    NN = fmaf(_w, (FV), NN);                             \
  }

#define TAPS5(I, F0, F1, F2, F3, F4, NN, DD) \
  TAP(xc##I, F0, cm4, NN, DD)                \
  TAP(xc##I, F1, cm1, NN, DD)                \
  TAP(xc##I, F2, cc0, NN, DD)                \
  TAP(xc##I, F3, cm1, NN, DD)                \
  TAP(xc##I, F4, cm4, NN, DD)

  // preload first row (dz=-2 -> zi=tz, dy=-2 -> yb-2)
  int rb = (tz * LYD + (yb - 2)) * PITCH + xw;
  float4 A = *(const float4*)&s[rb];
  float4 Bv = *(const float4*)&s[rb + 4];
  float4 C = *(const float4*)&s[rb + 8];

#pragma unroll 1
  for (int dz = -RADIUS; dz <= RADIUS; ++dz) {
    const float pz2 = AZ2 * (float)(dz * dz);
    const int zi = tz + RADIUS + dz;

#define ROW(DY)                                                              \
    {                                                                        \
      int _rn;                                                               \
      if ((DY) < 2) {                                                        \
        _rn = (zi * LYD + (yb + (DY) + 1)) * PITCH + xw;                     \
      } else {                                                               \
        int _zn = zi + 1;                                                    \
        _zn = _zn > (LZD - 1) ? (LZD - 1) : _zn;                             \
        _rn = (_zn * LYD + (yb - 2)) * PITCH + xw;                           \
      }                                                                      \
      float4 A2 = *(const float4*)&s[_rn];                                   \
      float4 B2 = *(const float4*)&s[_rn + 4];                               \
      float4 C2 = *(const float4*)&s[_rn + 8];                               \
      const float cc0 = EXP2_BIAS - (pz2 + AY2 * (float)((DY) * (DY)));      \
      const float cm1 = cc0 - AX2;                                           \
      const float cm4 = cc0 - AX2_4;                                         \
      const float f0 = A.x, f1 = A.y, f2 = A.z, f3 = A.w;                    \
      const float f4 = Bv.x, f5 = Bv.y, f6 = Bv.z, f7 = Bv.w;                \
      const float f8 = C.x, f9 = C.y, f10 = C.z, f11 = C.w;                  \
      TAPS5(0, f0, f1, f2, f3, f4, n0, e0)                                   \
      TAPS5(1, f1, f2, f3, f4, f5, n1, e1)                                   \
      TAPS5(2, f2, f3, f4, f5, f6, n2, e2)                                   \
      TAPS5(3, f3, f4, f5, f6, f7, n3, e3)                                   \
      TAPS5(4, f4, f5, f6, f7, f8, n4, e4)                                   \
      TAPS5(5, f5, f6, f7, f8, f9, n5, e5)                                   \
      TAPS5(6, f6, f7, f8, f9, f10, n6, e6)                                  \
      TAPS5(7, f7, f8, f9, f10, f11, n7, e7)                                 \
      A = A2; Bv = B2; C = C2;                                               \
    }

    ROW(-2)
    ROW(-1)
    ROW(0)
    ROW(1)
    ROW(2)
#undef ROW
  }

  float4 r0, r1;
  r0.x = n0 / e0; r0.y = n1 / e1; r0.z = n2 / e2; r0.w = n3 / e3;
  r1.x = n4 / e4; r1.y = n5 / e5; r1.z = n6 / e6; r1.w = n7 / e7;

  const int gz = z0 + tz, gy = y0 + ty;
  float* op = &out[(((size_t)b * N + gz) * N + gy) * N + (x0 + xw)];
  *(float4*)op = r0;
  *(float4*)(op + 4) = r1;
}

extern "C" void kernel_launch(void* const* d_in, const int* in_sizes, int n_in,
                              void* d_out, int out_size, void* d_ws, size_t ws_size,
                              hipStream_t stream) {
  const float* in = (const float*)d_in[0];
  const float* sx = (const float*)d_in[1];
  const float* sy = (const float*)d_in[2];
  const float* sz = (const float*)d_in[3];
  const float* cs = (const float*)d_in[4];
  float* out = (float*)d_out;

  dim3 grid(N / TX, N / TY, (N / TZ) * 2);  // 4 x 16 x 32
  bilateral3d_kernel<<<grid, 256, 0, stream>>>(in, sx, sy, sz, cs, out);
}

// Round 7
// 137.561 us; speedup vs baseline: 1.1512x; 1.1512x over previous
//
#include <hip/hip_runtime.h>
#include <hip/hip_bf16.h>

// 3D bilateral filter, radius 2 (125 taps), input (2,1,128,128,128) f32.
// v7: v5 shell (16x8x8 tile, 4 voxels/thread, 11.25 KB LDS, lb(256,4)) with
// packed-fp32 (VOP3P v_pk_*_f32) taps: 2 taps per instruction stream.
//  - dx-pairing: even voxels pack dx(-2,-1)+(0,+1), odd voxels dx(-1,0)+(+1,+2)
//    -> every pair is an even-aligned (f2k,f2k+1) VGPR pair via ds_read_b64.
//  - centers/row values pre-scaled by s=sqrt(2^23*log2e/(2*cs^2)) so the
//    range exponent is one pk_fma with neg: e = t*(-t) + CC  (= CC - (s*d)^2).
//  - Schraudolph w = asfloat(sat_u32(e)); sentinel 1e18 -> t^2 overflow ->
//    e=-inf -> w=0 == OOB mask (unchanged from v5).
// Per 2 taps: pk_add, pk_fma, 2x v_cvt_u32_f32, pk_add(den), pk_fma(num) = 6.
// Leftover scalar tap: 5 (fma uses -t trick). ~4.2 inst/tap vs v5's ~6.3.
// v6 lesson: keep v5's occupancy (small LDS, 4 voxels/thread, lb(256,4)).

#define RADIUS 2
#define N 128
#define TX 16
#define TY 8
#define TZ 8
#define PITCH (TX + 2 * RADIUS)      // 20 floats per row
#define LYD (TY + 2 * RADIUS)        // 12
#define LZD (TZ + 2 * RADIUS)        // 12
#define LDS_SIZE (PITCH * LYD * LZD) // 2880 floats = 11.25 KB

#define LOG2E 1.4426950408889634f
#define BIG 1.0e18f
#define EXP2_SCALE 8388608.0f        // 2^23
#define EXP2_BIAS 1065353216.0f      // 127 * 2^23

typedef float f32x2 __attribute__((ext_vector_type(2)));

__global__ __launch_bounds__(256, 4) void bilateral3d_kernel(
    const float* __restrict__ in, const float* __restrict__ p_sx,
    const float* __restrict__ p_sy, const float* __restrict__ p_sz,
    const float* __restrict__ p_cs, float* __restrict__ out) {
  __shared__ float s[LDS_SIZE];

  const int tid = threadIdx.x;
  const int x0 = blockIdx.x * TX;
  const int y0 = blockIdx.y * TY;
  const int zb = blockIdx.z;  // low 4 bits = z-tile, bit 4 = batch
  const int z0 = (zb & 15) * TZ;
  const int b = zb >> 4;

  const float* vol = in + (size_t)b * (N * N * N);

  // --- stage 20x12x12 halo tile (OOB -> sentinel) ---
  for (int i = tid; i < LDS_SIZE; i += 256) {
    int lx = i % PITCH;
    int t = i / PITCH;
    int ly = t % LYD;
    int lz = t / LYD;
    int gx = x0 + lx - RADIUS;
    int gy = y0 + ly - RADIUS;
    int gz = z0 + lz - RADIUS;
    float v = BIG;
    if ((unsigned)gx < N && (unsigned)gy < N && (unsigned)gz < N)
      v = vol[((size_t)gz * N + gy) * N + gx];
    s[i] = v;
  }
  __syncthreads();

  const int tx = tid & 3;         // x-group: voxels x0+4tx .. x0+4tx+3
  const int ty = (tid >> 2) & 7;
  const int tz = tid >> 5;

  const float sxv = p_sx[0], syv = p_sy[0], szv = p_sz[0], csv = p_cs[0];
  const float AX2 = EXP2_SCALE * LOG2E / (2.0f * sxv * sxv);
  const float AY2 = EXP2_SCALE * LOG2E / (2.0f * syv * syv);
  const float AZ2 = EXP2_SCALE * LOG2E / (2.0f * szv * szv);
  const float AX2_4 = 4.0f * AX2;
  // range scale: (s*d)^2 = 2^23*log2e*d^2/(2cs^2)
  const float sR = __builtin_sqrtf(EXP2_SCALE * LOG2E / (2.0f * csv * csv));
  f32x2 S2;
  S2.x = sR;
  S2.y = sR;

  const int xw = 4 * tx;  // word offset within row of this thread's tap window

  // centers: words [xw+2 .. xw+5] of the (dz=0,dy=0) row, pre-scaled by sR
  const int cbase = ((tz + RADIUS) * LYD + (ty + RADIUS)) * PITCH + xw;
  const float xs0 = s[cbase + 2] * sR;
  const float xs1 = s[cbase + 3] * sR;
  const float xs2 = s[cbase + 4] * sR;
  const float xs3 = s[cbase + 5] * sR;
  f32x2 XS0, XS1, XS2, XS3;
  XS0.x = xs0; XS0.y = xs0;
  XS1.x = xs1; XS1.y = xs1;
  XS2.x = xs2; XS2.y = xs2;
  XS3.x = xs3; XS3.y = xs3;

  f32x2 NU0 = {0.f, 0.f}, NU1 = {0.f, 0.f}, NU2 = {0.f, 0.f}, NU3 = {0.f, 0.f};
  f32x2 DE0 = {0.f, 0.f}, DE1 = {0.f, 0.f}, DE2 = {0.f, 0.f}, DE3 = {0.f, 0.f};
  float ns0 = 0, ns1 = 0, ns2 = 0, ns3 = 0;  // scalar-tap accumulators
  float es0 = 0, es1 = 0, es2 = 0, es3 = 0;

  // packed tap pair: t = XS - GS; e = t*(-t) + CC; w = sat_u32(e) bits;
  // den += w; num += w * Graw
#define PK(XS2V, GS, GR, CC2, NUM2, DEN2)                                \
  {                                                                      \
    f32x2 _t, _e;                                                        \
    asm("v_pk_add_f32 %0, %1, %2 neg_lo:[0,1] neg_hi:[0,1]"              \
        : "=v"(_t) : "v"(XS2V), "v"(GS));                                \
    asm("v_pk_fma_f32 %0, %1, %1, %2 neg_lo:[0,1,0] neg_hi:[0,1,0]"      \
        : "=v"(_e) : "v"(_t), "v"(CC2));                                 \
    unsigned _ql, _qh;                                                   \
    asm("v_cvt_u32_f32 %0, %1" : "=v"(_ql) : "v"(_e.x));                 \
    asm("v_cvt_u32_f32 %0, %1" : "=v"(_qh) : "v"(_e.y));                 \
    f32x2 _w;                                                            \
    _w.x = __uint_as_float(_ql);                                         \
    _w.y = __uint_as_float(_qh);                                         \
    asm("v_pk_add_f32 %0, %0, %1" : "+v"(DEN2) : "v"(_w));               \
    asm("v_pk_fma_f32 %0, %1, %2, %0" : "+v"(NUM2) : "v"(_w), "v"(GR));  \
  }

  // scalar tap (leftover, |dx|=2): 5 insts
#define SC(XSV, FS, FR, CC, NN, EE)                      \
  {                                                      \
    float _t = (XSV) - (FS);                             \
    float _f = fmaf(_t, -_t, (CC));                      \
    unsigned _q;                                         \
    asm("v_cvt_u32_f32 %0, %1" : "=v"(_q) : "v"(_f));    \
    float _w = __uint_as_float(_q);                      \
    EE += _w;                                            \
    NN = fmaf(_w, (FR), NN);                             \
  }

#pragma unroll 1
  for (int dz = -RADIUS; dz <= RADIUS; ++dz) {
    const float pz2 = AZ2 * (float)(dz * dz);
    const int zrow = (tz + RADIUS + dz) * LYD;
#pragma unroll
    for (int dy = -RADIUS; dy <= RADIUS; ++dy) {
      const float cc0 = EXP2_BIAS - (pz2 + AY2 * (float)(dy * dy));
      const float cm1 = cc0 - AX2;
      const float cm4 = cc0 - AX2_4;
      f32x2 P41, P01, P10, P14;
      P41.x = cm4; P41.y = cm1;  // dx (-2,-1)
      P01.x = cc0; P01.y = cm1;  // dx ( 0,+1)
      P10.x = cm1; P10.y = cc0;  // dx (-1, 0)
      P14.x = cm1; P14.y = cm4;  // dx (+1,+2)

      const int rb = (zrow + (ty + RADIUS + dy)) * PITCH + xw;
      const f32x2 G0 = *(const f32x2*)&s[rb];
      const f32x2 G1 = *(const f32x2*)&s[rb + 2];
      const f32x2 G2 = *(const f32x2*)&s[rb + 4];
      const f32x2 G3 = *(const f32x2*)&s[rb + 6];
      f32x2 Gs0, Gs1, Gs2, Gs3;
      asm("v_pk_mul_f32 %0, %1, %2" : "=v"(Gs0) : "v"(G0), "v"(S2));
      asm("v_pk_mul_f32 %0, %1, %2" : "=v"(Gs1) : "v"(G1), "v"(S2));
      asm("v_pk_mul_f32 %0, %1, %2" : "=v"(Gs2) : "v"(G2), "v"(S2));
      asm("v_pk_mul_f32 %0, %1, %2" : "=v"(Gs3) : "v"(G3), "v"(S2));

      // voxel 0 (center f2): G0 -> dx(-2,-1), G1 -> dx(0,+1), f4 -> dx+2
      PK(XS0, Gs0, G0, P41, NU0, DE0)
      PK(XS0, Gs1, G1, P01, NU0, DE0)
      SC(xs0, Gs2.x, G2.x, cm4, ns0, es0)
      // voxel 1 (center f3): f1 -> dx-2, G1 -> dx(-1,0), G2 -> dx(+1,+2)
      SC(xs1, Gs0.y, G0.y, cm4, ns1, es1)
      PK(XS1, Gs1, G1, P10, NU1, DE1)
      PK(XS1, Gs2, G2, P14, NU1, DE1)
      // voxel 2 (center f4): G1 -> dx(-2,-1), G2 -> dx(0,+1), f6 -> dx+2
      PK(XS2, Gs1, G1, P41, NU2, DE2)
      PK(XS2, Gs2, G2, P01, NU2, DE2)
      SC(xs2, Gs3.x, G3.x, cm4, ns2, es2)
      // voxel 3 (center f5): f3 -> dx-2, G2 -> dx(-1,0), G3 -> dx(+1,+2)
      SC(xs3, Gs1.y, G1.y, cm4, ns3, es3)
      PK(XS3, Gs2, G2, P10, NU3, DE3)
      PK(XS3, Gs3, G3, P14, NU3, DE3)
    }
  }

  float4 r;
  r.x = (NU0.x + NU0.y + ns0) / (DE0.x + DE0.y + es0);
  r.y = (NU1.x + NU1.y + ns1) / (DE1.x + DE1.y + es1);
  r.z = (NU2.x + NU2.y + ns2) / (DE2.x + DE2.y + es2);
  r.w = (NU3.x + NU3.y + ns3) / (DE3.x + DE3.y + es3);

  const int gz = z0 + tz, gy = y0 + ty;
  *(float4*)&out[(((size_t)b * N + gz) * N + gy) * N + (x0 + xw)] = r;
}

extern "C" void kernel_launch(void* const* d_in, const int* in_sizes, int n_in,
                              void* d_out, int out_size, void* d_ws, size_t ws_size,
                              hipStream_t stream) {
  const float* in = (const float*)d_in[0];
  const float* sx = (const float*)d_in[1];
  const float* sy = (const float*)d_in[2];
  const float* sz = (const float*)d_in[3];
  const float* cs = (const float*)d_in[4];
  float* out = (float*)d_out;

  dim3 grid(N / TX, N / TY, (N / TZ) * 2);  // 8 x 16 x 32
  bilateral3d_kernel<<<grid, 256, 0, stream>>>(in, sx, sy, sz, cs, out);
}